// Round 8
// baseline (309.672 us; speedup 1.0000x reference)
//
#include <hip/hip_runtime.h>
#include <hip/hip_bf16.h>

#define NNODES   163842
#define INF      32
#define OUTF     64
#define NPOS     25
#define KTOT     800
#define MT       128      // nodes per block (8 waves x 16)
#define NTHREADS 512
#define NWAVES   8
#define WSZ      54614    // window rows: 163842 = 3*54614, 3.41 MB f16 < 4 MB L2/XCD

typedef float    f32x4 __attribute__((ext_vector_type(4)));
typedef _Float16 f16x8 __attribute__((ext_vector_type(8)));

typedef const __attribute__((address_space(1))) void GV;
typedef __attribute__((address_space(3))) void LV;

// ---------------- precompute: xh = f16(x); wh = per-lane-swizzled f16 W ----------------
// wh layout: frag f=(p*4+nb), lane l, elem j:
//   wh[(f*64+l)*8+j] = W[16*nb+(l&15)][p*32+(l>>4)*8+j]
__global__ void cvt_kernel(const float* __restrict__ x, const float* __restrict__ W,
                           _Float16* __restrict__ xh, _Float16* __restrict__ wh) {
    int tid = blockIdx.x * blockDim.x + threadIdx.x;
    int stride = gridDim.x * blockDim.x;
    const int nx8 = NNODES * INF / 8;
    const f32x4* x4 = (const f32x4*)x;
    f16x8* xh8 = (f16x8*)xh;
    for (int j = tid; j < nx8; j += stride) {
        f32x4 a = x4[2*j], b = x4[2*j+1];
        f16x8 o;
        #pragma unroll
        for (int k = 0; k < 4; ++k) { o[k] = (_Float16)a[k]; o[4+k] = (_Float16)b[k]; }
        xh8[j] = o;
    }
    f16x8* wh8 = (f16x8*)wh;
    for (int t = tid; t < NPOS * 4 * 64; t += stride) {
        const int l  = t & 63;
        const int nb = (t >> 6) & 3;
        const int p  = t >> 8;
        const int row = 16*nb + (l & 15);
        const int kb  = p*32 + (l >> 4)*8;
        const float* src = W + row * KTOT + kb;
        f16x8 o;
        #pragma unroll
        for (int j = 0; j < 8; ++j) o[j] = (_Float16)src[j];
        wh8[t] = o;
    }
}

// ------- fused gather + MFMA, WINDOWED: only gathers idx in [lo, lo+WSZ) -------
// Out-of-window verts: address clamped to window base row (single hot line),
// weight zeroed -> exact partial sum. Phase 0 writes out+bias, else out += acc.
__launch_bounds__(NTHREADS, 1)
__global__ void conv_mfma(const int* __restrict__ nidx, const float* __restrict__ nwt,
                          const _Float16* __restrict__ xh, const _Float16* __restrict__ wh,
                          const float* __restrict__ bias, float* __restrict__ out,
                          int lo, int phase) {
    __shared__ __align__(16) _Float16 whl[NPOS * 4 * 64 * 8];  // 102,400 B
    __shared__ int      idxs[MT * 75];                         // 38,400 B
    __shared__ _Float16 wtsl[MT * 75];                         // 19,200 B -> 160,000 total

    const int tid  = threadIdx.x;
    const int blk  = blockIdx.x;
    const int lane = tid & 63;
    const int wave = tid >> 6;

    // stage all W-frags into LDS: 100 x 1KB linear wave-loads (dest = base + lane*16)
    for (int i = wave; i < NPOS * 4; i += NWAVES) {
        __builtin_amdgcn_global_load_lds((GV*)((const char*)wh + i * 1024 + lane * 16),
                                         (LV*)((char*)whl + i * 1024), 16, 0, 0);
    }
    // stage idx + f16 weights, coalesced; zero-fill past NNODES
    {
        const long gbase = (long)blk * (MT * 75);
        const long tot   = (long)NNODES * 75;
        for (int i = tid; i < MT * 75; i += NTHREADS) {
            long g = gbase + i;
            bool ok = g < tot;
            idxs[i] = ok ? nidx[g] : 0;
            wtsl[i] = ok ? (_Float16)nwt[g] : (_Float16)0.0f;
        }
    }

    const int arow  = lane & 15;      // node within wave's 16
    const int kgrp  = lane >> 4;      // channel octet
    const int irow  = (wave * 16 + arow) * 75;
    const int node0 = blk * MT + wave * 16;
    const _Float16* xg = xh + kgrp * 8;

    __syncthreads();   // compiler drains vmcnt(0)+lgkmcnt(0) here -> FIFO clean

    f32x4 acc0 = {0,0,0,0}, acc1 = {0,0,0,0}, acc2 = {0,0,0,0}, acc3 = {0,0,0,0};
    // 4-deep gather ring, named registers (asm outputs can't be sunk/rematerialized)
    f16x8 g00, g01, g02, g10, g11, g12, g20, g21, g22, g30, g31, g32;

// in-window predicate; clamp OOW address to window base row (merges to 1 line)
#define ISSUE(P, S) do {                                                        \
        const int _p = (P);                                                     \
        int _i0 = idxs[irow + _p*3 + 0];                                        \
        int _i1 = idxs[irow + _p*3 + 1];                                        \
        int _i2 = idxs[irow + _p*3 + 2];                                        \
        _i0 = ((unsigned)(_i0 - lo) < (unsigned)WSZ) ? _i0 : lo;                \
        _i1 = ((unsigned)(_i1 - lo) < (unsigned)WSZ) ? _i1 : lo;                \
        _i2 = ((unsigned)(_i2 - lo) < (unsigned)WSZ) ? _i2 : lo;                \
        const _Float16* _a0 = xg + (long)_i0 * INF;                             \
        const _Float16* _a1 = xg + (long)_i1 * INF;                             \
        const _Float16* _a2 = xg + (long)_i2 * INF;                             \
        asm volatile("global_load_dwordx4 %0, %1, off" : "=&v"(g##S##0) : "v"(_a0)); \
        asm volatile("global_load_dwordx4 %0, %1, off" : "=&v"(g##S##1) : "v"(_a1)); \
        asm volatile("global_load_dwordx4 %0, %1, off" : "=&v"(g##S##2) : "v"(_a2)); \
    } while (0)

// STEP: LDS B-frags + windowed weights first, counted wait, MFMA, re-issue
#define STEP(P, S, VM, PI) do {                                                 \
        const int _p = (P);                                                     \
        const f16x8* _bwp = (const f16x8*)whl + _p * 256 + lane;                \
        const f16x8 _b0 = _bwp[0];                                              \
        const f16x8 _b1 = _bwp[64];                                             \
        const f16x8 _b2 = _bwp[128];                                            \
        const f16x8 _b3 = _bwp[192];                                            \
        const int _j0 = idxs[irow + _p*3 + 0];                                  \
        const int _j1 = idxs[irow + _p*3 + 1];                                  \
        const int _j2 = idxs[irow + _p*3 + 2];                                  \
        const _Float16 _z = (_Float16)0.0f;                                     \
        const _Float16 _w0 = ((unsigned)(_j0 - lo) < (unsigned)WSZ) ? wtsl[irow + _p*3 + 0] : _z; \
        const _Float16 _w1 = ((unsigned)(_j1 - lo) < (unsigned)WSZ) ? wtsl[irow + _p*3 + 1] : _z; \
        const _Float16 _w2 = ((unsigned)(_j2 - lo) < (unsigned)WSZ) ? wtsl[irow + _p*3 + 2] : _z; \
        asm volatile("s_waitcnt vmcnt(" #VM ")" ::: "memory");                  \
        __builtin_amdgcn_sched_barrier(0);                                      \
        const f16x8 _af = g##S##0 * _w0 + g##S##1 * _w1 + g##S##2 * _w2;        \
        acc0 = __builtin_amdgcn_mfma_f32_16x16x32_f16(_b0, _af, acc0, 0, 0, 0); \
        acc1 = __builtin_amdgcn_mfma_f32_16x16x32_f16(_b1, _af, acc1, 0, 0, 0); \
        acc2 = __builtin_amdgcn_mfma_f32_16x16x32_f16(_b2, _af, acc2, 0, 0, 0); \
        acc3 = __builtin_amdgcn_mfma_f32_16x16x32_f16(_b3, _af, acc3, 0, 0, 0); \
        __builtin_amdgcn_sched_barrier(0);                                      \
        if ((PI) >= 0) ISSUE((PI), S);                                          \
        __builtin_amdgcn_sched_barrier(0);                                      \
    } while (0)

    ISSUE(0, 0); ISSUE(1, 1); ISSUE(2, 2); ISSUE(3, 3);   // 12 gathers in flight

    for (int pp = 0; pp < 20; pp += 4) {
        STEP(pp + 0, 0, 9, pp + 4);
        STEP(pp + 1, 1, 9, pp + 5);
        STEP(pp + 2, 2, 9, pp + 6);
        STEP(pp + 3, 3, 9, pp + 7);
    }
    STEP(20, 0, 9, 24);
    STEP(21, 1, 9, -1);
    STEP(22, 2, 6, -1);
    STEP(23, 3, 3, -1);
    STEP(24, 0, 0, -1);

#undef ISSUE
#undef STEP

    // epilogue: swapped-operand D=[outcol][node] (lineage-verified r4-r7):
    // col(lane&15)=node, rows 4*kgrp+r = outcol -> f32x4 per nb.
    // phase 0: out = acc + bias; else: out += acc (RMW; launches serialize).
    const int node = node0 + arow;
    if (node < NNODES) {
        #pragma unroll
        for (int nb = 0; nb < 4; ++nb) {
            const int cb = 16*nb + 4*kgrp;
            float* dst = out + (long)node * OUTF + cb;
            const f32x4 a = (nb == 0 ? acc0 : nb == 1 ? acc1 : nb == 2 ? acc2 : acc3);
            f32x4 base4;
            if (phase == 0) base4 = *(const f32x4*)(bias + cb);
            else            base4 = *(const f32x4*)dst;
            f32x4 o;
            #pragma unroll
            for (int r = 0; r < 4; ++r) o[r] = a[r] + base4[r];
            *(f32x4*)dst = o;
        }
    }
}

// ---------------- safety fallback (no workspace needed), fp32 ----------------
__global__ void conv_fallback(const float* __restrict__ x, const int* __restrict__ nidx,
                              const float* __restrict__ nwt, const float* __restrict__ W,
                              const float* __restrict__ bias, float* __restrict__ out) {
    __shared__ float feat[KTOT];
    const int n = blockIdx.x;
    const int t = threadIdx.x;   // 64
    for (int e = t; e < KTOT; e += 64) {
        const int p = e >> 5, c = e & 31;
        const int ib = n * 75 + p * 3;
        float a = 0.0f;
        #pragma unroll
        for (int v = 0; v < 3; ++v)
            a += nwt[ib+v] * x[nidx[ib+v] * INF + c];
        feat[e] = a;
    }
    __syncthreads();
    float a = bias[t];
    const float* wr = W + t * KTOT;
    for (int k = 0; k < KTOT; ++k) a += feat[k] * wr[k];
    out[(long)n * OUTF + t] = a;
}

extern "C" void kernel_launch(void* const* d_in, const int* in_sizes, int n_in,
                              void* d_out, int out_size, void* d_ws, size_t ws_size,
                              hipStream_t stream) {
    const float* x    = (const float*)d_in[0];
    const int*   nidx = (const int*)  d_in[1];
    const float* nwt  = (const float*)d_in[2];
    const float* W    = (const float*)d_in[3];
    const float* bias = (const float*)d_in[4];
    float* out = (float*)d_out;

    const size_t need = (size_t)NNODES * INF * 2 + (size_t)NPOS * 4 * 64 * 8 * 2;
    if (ws_size < need) {
        conv_fallback<<<NNODES, 64, 0, stream>>>(x, nidx, nwt, W, bias, out);
        return;
    }

    _Float16* xh = (_Float16*)d_ws;
    _Float16* wh = xh + (size_t)NNODES * INF;

    cvt_kernel<<<1024, 256, 0, stream>>>(x, W, xh, wh);
    const int nblocks = (NNODES + MT - 1) / MT;   // 1281
    conv_mfma<<<nblocks, NTHREADS, 0, stream>>>(nidx, nwt, xh, wh, bias, out, 0,       0);
    conv_mfma<<<nblocks, NTHREADS, 0, stream>>>(nidx, nwt, xh, wh, bias, out, WSZ,     1);
    conv_mfma<<<nblocks, NTHREADS, 0, stream>>>(nidx, nwt, xh, wh, bias, out, 2 * WSZ, 2);
}

// Round 9
// 179.605 us; speedup vs baseline: 1.7242x; 1.7242x over previous
//
#include <hip/hip_runtime.h>
#include <hip/hip_bf16.h>
#include <type_traits>

#define NNODES   163842
#define INF      32
#define OUTF     64
#define NPOS     25
#define KTOT     800
#define MT       64       // nodes per block (4 waves x 16 nodes)
#define NTHREADS 256

typedef float    f32x4 __attribute__((ext_vector_type(4)));
typedef _Float16 f16x8 __attribute__((ext_vector_type(8)));

template<int N> using IC = std::integral_constant<int, N>;

typedef const __attribute__((address_space(1))) void GV;
typedef __attribute__((address_space(3))) void LV;

template<int N>
__device__ __forceinline__ void waitv_sb() {
    static_assert(N == 0 || N == 7 || N == 14, "bad vmcnt");
    if constexpr (N == 14)      asm volatile("s_waitcnt vmcnt(14)" ::: "memory");
    else if constexpr (N == 7)  asm volatile("s_waitcnt vmcnt(7)"  ::: "memory");
    else                        asm volatile("s_waitcnt vmcnt(0)"  ::: "memory");
    __builtin_amdgcn_sched_barrier(0);   // rule #18: fence MFMA/ds_read hoisting
}

// ---------------- precompute: xh = f16(x); wh = per-lane-swizzled f16 W ----------------
// wh layout: frag f=(p*4+nb), lane l, elem j:
//   wh[(f*64+l)*8+j] = W[16*nb+(l&15)][p*32+(l>>4)*8+j]
__global__ void cvt_kernel(const float* __restrict__ x, const float* __restrict__ W,
                           _Float16* __restrict__ xh, _Float16* __restrict__ wh) {
    int tid = blockIdx.x * blockDim.x + threadIdx.x;
    int stride = gridDim.x * blockDim.x;
    const int nx8 = NNODES * INF / 8;
    const f32x4* x4 = (const f32x4*)x;
    f16x8* xh8 = (f16x8*)xh;
    for (int j = tid; j < nx8; j += stride) {
        f32x4 a = x4[2*j], b = x4[2*j+1];
        f16x8 o;
        #pragma unroll
        for (int k = 0; k < 4; ++k) { o[k] = (_Float16)a[k]; o[4+k] = (_Float16)b[k]; }
        xh8[j] = o;
    }
    f16x8* wh8 = (f16x8*)wh;
    for (int t = tid; t < NPOS * 4 * 64; t += stride) {
        const int l  = t & 63;
        const int nb = (t >> 6) & 3;
        const int p  = t >> 8;
        const int row = 16*nb + (l & 15);
        const int kb  = p*32 + (l >> 4)*8;
        const float* src = W + row * KTOT + kb;
        f16x8 o;
        #pragma unroll
        for (int j = 0; j < 8; ++j) o[j] = (_Float16)src[j];
        wh8[t] = o;
    }
}

// ---------------- fused gather + MFMA: LDS-bounced gather pipeline ----------------
__launch_bounds__(NTHREADS, 2)
__global__ void conv_mfma(const int* __restrict__ nidx, const float* __restrict__ nwt,
                          const _Float16* __restrict__ xh, const _Float16* __restrict__ wh,
                          const float* __restrict__ bias, float* __restrict__ out) {
    __shared__ int      idxs[MT * 75];                    // 19200 B
    __shared__ _Float16 wtsl[MT * 76];                    // 9728 B
    __shared__ __align__(16) _Float16 feat[4][4][3][512]; // 49152 B: [wave][slot][vert][lane*8]

    const int tid = threadIdx.x;
    const int blk = blockIdx.x;

    // stage idx + f16 weights, coalesced; zero-fill past NNODES
    {
        const long gbase = (long)blk * (MT * 75);
        const long tot   = (long)NNODES * 75;
        #pragma unroll
        for (int it = 0; it < (MT * 75 + NTHREADS - 1) / NTHREADS; ++it) {
            int i = tid + it * NTHREADS;
            if (i < MT * 75) {
                long g = gbase + i;
                bool ok = g < tot;
                int n = i / 75, t = i % 75;
                idxs[i] = ok ? nidx[g] : 0;
                wtsl[n * 76 + t] = ok ? (_Float16)nwt[g] : (_Float16)0.0f;
            }
        }
    }

    const int lane = tid & 63;
    const int wave = tid >> 6;
    const int arow = lane & 15;       // node within wave's 16
    const int kgrp = lane >> 4;       // channel octet
    const int irow = (wave * 16 + arow) * 75;
    const int wrow = (wave * 16 + arow) * 76;
    const int node0 = blk * MT + wave * 16;
    const _Float16* xg  = xh + kgrp * 8;
    const char*     whl = (const char*)wh + (size_t)lane * 16;  // +p*4096 +nb*1024

    __syncthreads();

    f32x4 acc[4] = {{0,0,0,0},{0,0,0,0},{0,0,0,0},{0,0,0,0}};
    f16x8 bw[4][4];   // B-frag ring, statically indexed (full unroll)

    // one bundle = 3 LDS-DMA gathers + 4 asm B-loads = 7 vmem, order pinned
    auto ISSUE = [&](auto pc) {
        constexpr int p = decltype(pc)::value;
        constexpr int s = p & 3;
        #pragma unroll
        for (int v = 0; v < 3; ++v) {
            const int idx = idxs[irow + p * 3 + v];
            const _Float16* src = xg + (long)idx * INF;
            __builtin_amdgcn_global_load_lds((GV*)src, (LV*)(&feat[wave][s][v][0]), 16, 0, 0);
        }
        const char* a = whl + p * 4096;
        asm volatile(
            "global_load_dwordx4 %0, %4, off\n\t"
            "global_load_dwordx4 %1, %4, off offset:1024\n\t"
            "global_load_dwordx4 %2, %4, off offset:2048\n\t"
            "global_load_dwordx4 %3, %4, off offset:3072"
            : "=&v"(bw[s][0]), "=&v"(bw[s][1]), "=&v"(bw[s][2]), "=&v"(bw[s][3])
            : "v"(a)
            : "memory");
        __builtin_amdgcn_sched_barrier(0);
    };

    auto STEP = [&](auto pc) {
        constexpr int p = decltype(pc)::value;
        waitv_sb<(p <= 22) ? 14 : ((p == 23) ? 7 : 0)>();   // bundle p fully retired
        constexpr int s = p & 3;
        const f16x8 v0 = *(const f16x8*)&feat[wave][s][0][lane * 8];
        const f16x8 v1 = *(const f16x8*)&feat[wave][s][1][lane * 8];
        const f16x8 v2 = *(const f16x8*)&feat[wave][s][2][lane * 8];
        const _Float16 w0 = wtsl[wrow + p * 3 + 0];
        const _Float16 w1 = wtsl[wrow + p * 3 + 1];
        const _Float16 w2 = wtsl[wrow + p * 3 + 2];
        const f16x8 af = v0 * w0 + v1 * w1 + v2 * w2;
        #pragma unroll
        for (int nb = 0; nb < 4; ++nb)
            acc[nb] = __builtin_amdgcn_mfma_f32_16x16x32_f16(bw[s][nb], af, acc[nb], 0, 0, 0);
        __builtin_amdgcn_sched_barrier(0);
        if constexpr (p + 3 < NPOS) ISSUE(IC<p + 3>{});
    };

    ISSUE(IC<0>{}); ISSUE(IC<1>{}); ISSUE(IC<2>{});   // 21 vmem in flight

    STEP(IC<0>{});  STEP(IC<1>{});  STEP(IC<2>{});  STEP(IC<3>{});  STEP(IC<4>{});
    STEP(IC<5>{});  STEP(IC<6>{});  STEP(IC<7>{});  STEP(IC<8>{});  STEP(IC<9>{});
    STEP(IC<10>{}); STEP(IC<11>{}); STEP(IC<12>{}); STEP(IC<13>{}); STEP(IC<14>{});
    STEP(IC<15>{}); STEP(IC<16>{}); STEP(IC<17>{}); STEP(IC<18>{}); STEP(IC<19>{});
    STEP(IC<20>{}); STEP(IC<21>{}); STEP(IC<22>{}); STEP(IC<23>{}); STEP(IC<24>{});

    // epilogue: swapped-operand D=[outcol][node] (verified rounds 1-4 lineage):
    // col(lane&15)=node, rows 4*kgrp+r = outcol -> f32x4 store per nb
    const int node = node0 + arow;
    if (node < NNODES) {
        #pragma unroll
        for (int nb = 0; nb < 4; ++nb) {
            const int cb = 16*nb + 4*kgrp;
            const f32x4 b4 = *(const f32x4*)(bias + cb);
            f32x4 o;
            #pragma unroll
            for (int r = 0; r < 4; ++r) o[r] = acc[nb][r] + b4[r];
            *(f32x4*)(out + (long)node * OUTF + cb) = o;
        }
    }
}

// ---------------- safety fallback (no workspace needed), fp32 ----------------
__global__ void conv_fallback(const float* __restrict__ x, const int* __restrict__ nidx,
                              const float* __restrict__ nwt, const float* __restrict__ W,
                              const float* __restrict__ bias, float* __restrict__ out) {
    __shared__ float feat[KTOT];
    const int n = blockIdx.x;
    const int t = threadIdx.x;   // 64
    for (int e = t; e < KTOT; e += 64) {
        const int p = e >> 5, c = e & 31;
        const int ib = n * 75 + p * 3;
        float a = 0.0f;
        #pragma unroll
        for (int v = 0; v < 3; ++v)
            a += nwt[ib+v] * x[nidx[ib+v] * INF + c];
        feat[e] = a;
    }
    __syncthreads();
    float a = bias[t];
    const float* wr = W + t * KTOT;
    for (int k = 0; k < KTOT; ++k) a += feat[k] * wr[k];
    out[(long)n * OUTF + t] = a;
}

extern "C" void kernel_launch(void* const* d_in, const int* in_sizes, int n_in,
                              void* d_out, int out_size, void* d_ws, size_t ws_size,
                              hipStream_t stream) {
    const float* x    = (const float*)d_in[0];
    const int*   nidx = (const int*)  d_in[1];
    const float* nwt  = (const float*)d_in[2];
    const float* W    = (const float*)d_in[3];
    const float* bias = (const float*)d_in[4];
    float* out = (float*)d_out;

    const size_t need = (size_t)NNODES * INF * 2 + (size_t)NPOS * 4 * 64 * 8 * 2;
    if (ws_size < need) {
        conv_fallback<<<NNODES, 64, 0, stream>>>(x, nidx, nwt, W, bias, out);
        return;
    }

    _Float16* xh = (_Float16*)d_ws;
    _Float16* wh = xh + (size_t)NNODES * INF;

    cvt_kernel<<<1024, NTHREADS, 0, stream>>>(x, W, xh, wh);
    const int nblocks = (NNODES + MT - 1) / MT;   // 2561
    conv_mfma<<<nblocks, NTHREADS, 0, stream>>>(nidx, nwt, xh, wh, bias, out);
}

// Round 10
// 177.108 us; speedup vs baseline: 1.7485x; 1.0141x over previous
//
#include <hip/hip_runtime.h>
#include <hip/hip_bf16.h>
#include <type_traits>

#define NNODES   163842
#define INF      32
#define OUTF     64
#define NPOS     25
#define KTOT     800
#define MT       64       // nodes per block (4 waves x 16 nodes)
#define NTHREADS 256

typedef float    f32x4 __attribute__((ext_vector_type(4)));
typedef _Float16 f16x8 __attribute__((ext_vector_type(8)));

template<int N> using IC = std::integral_constant<int, N>;

typedef const __attribute__((address_space(1))) void GV;
typedef __attribute__((address_space(3))) void LV;

template<int N>
__device__ __forceinline__ void waitv_sb() {
    static_assert(N == 0 || N == 7 || N == 14, "bad vmcnt");
    if constexpr (N == 14)      asm volatile("s_waitcnt vmcnt(14)" ::: "memory");
    else if constexpr (N == 7)  asm volatile("s_waitcnt vmcnt(7)"  ::: "memory");
    else                        asm volatile("s_waitcnt vmcnt(0)"  ::: "memory");
    __builtin_amdgcn_sched_barrier(0);   // rule #18: fence MFMA/ds_read hoisting
}

// ---------------- precompute: xh = f16(x); wh = per-lane-swizzled f16 W ----------------
// wh layout: frag f=(p*4+nb), lane l, elem j:
//   wh[(f*64+l)*8+j] = W[16*nb+(l&15)][p*32+(l>>4)*8+j]
__global__ void cvt_kernel(const float* __restrict__ x, const float* __restrict__ W,
                           _Float16* __restrict__ xh, _Float16* __restrict__ wh) {
    int tid = blockIdx.x * blockDim.x + threadIdx.x;
    int stride = gridDim.x * blockDim.x;
    const int nx8 = NNODES * INF / 8;
    const f32x4* x4 = (const f32x4*)x;
    f16x8* xh8 = (f16x8*)xh;
    for (int j = tid; j < nx8; j += stride) {
        f32x4 a = x4[2*j], b = x4[2*j+1];
        f16x8 o;
        #pragma unroll
        for (int k = 0; k < 4; ++k) { o[k] = (_Float16)a[k]; o[4+k] = (_Float16)b[k]; }
        xh8[j] = o;
    }
    f16x8* wh8 = (f16x8*)wh;
    for (int t = tid; t < NPOS * 4 * 64; t += stride) {
        const int l  = t & 63;
        const int nb = (t >> 6) & 3;
        const int p  = t >> 8;
        const int row = 16*nb + (l & 15);
        const int kb  = p*32 + (l >> 4)*8;
        const float* src = W + row * KTOT + kb;
        f16x8 o;
        #pragma unroll
        for (int j = 0; j < 8; ++j) o[j] = (_Float16)src[j];
        wh8[t] = o;
    }
}

// ---------------- fused gather + MFMA: LDS-bounced gather pipeline ----------------
// NEW vs r5: gather lane-map is ADJACENT-COALESCED: lane l fetches node (l>>2),
// chunk (l&3)^swz -> 4 adjacent lanes cover one contiguous 64B row (classic
// segment coalescing). LDS slab becomes node-major; MFMA-side read applies the
// same chunk-XOR involution (<=2-way banks). Math identical to r5.
__launch_bounds__(NTHREADS, 2)
__global__ void conv_mfma(const int* __restrict__ nidx, const float* __restrict__ nwt,
                          const _Float16* __restrict__ xh, const _Float16* __restrict__ wh,
                          const float* __restrict__ bias, float* __restrict__ out) {
    __shared__ int      idxs[MT * 75];                    // 19200 B
    __shared__ _Float16 wtsl[MT * 76];                    // 9728 B
    __shared__ __align__(16) _Float16 feat[4][4][3][512]; // 49152 B: [wave][slot][vert][node-major]

    const int tid = threadIdx.x;
    const int blk = blockIdx.x;

    // stage idx + f16 weights, coalesced; zero-fill past NNODES
    {
        const long gbase = (long)blk * (MT * 75);
        const long tot   = (long)NNODES * 75;
        #pragma unroll
        for (int it = 0; it < (MT * 75 + NTHREADS - 1) / NTHREADS; ++it) {
            int i = tid + it * NTHREADS;
            if (i < MT * 75) {
                long g = gbase + i;
                bool ok = g < tot;
                int n = i / 75, t = i % 75;
                idxs[i] = ok ? nidx[g] : 0;
                wtsl[n * 76 + t] = ok ? (_Float16)nwt[g] : (_Float16)0.0f;
            }
        }
    }

    const int lane = tid & 63;
    const int wave = tid >> 6;
    const int arow = lane & 15;       // MFMA-read node / A row / W row offset
    const int kgrp = lane >> 4;       // MFMA-read channel octet
    // gather-side mapping: 4 adjacent lanes = 1 node row (64B)
    const int gn     = lane >> 2;     // node within wave's 16
    const int c_load = (lane & 3) ^ (gn & 3) ^ ((gn >> 2) & 3);  // swizzled chunk
    const int irow2  = (wave * 16 + gn) * 75;
    // MFMA-read LDS offset (elems): node arow, chunk kgrp lives at swizzled slot
    const int roff = arow * 32 + ((kgrp ^ (arow & 3) ^ ((arow >> 2) & 3)) * 8);

    const int irow = (wave * 16 + arow) * 75;
    const int wrow = (wave * 16 + arow) * 76;
    const int node0 = blk * MT + wave * 16;
    const _Float16* xg  = xh + c_load * 8;                      // + idx*INF per gather
    const char*     whl = (const char*)wh + (size_t)lane * 16;  // +p*4096 +nb*1024

    __syncthreads();

    f32x4 acc[4] = {{0,0,0,0},{0,0,0,0},{0,0,0,0},{0,0,0,0}};
    f16x8 bw[4][4];   // B-frag ring, statically indexed (full unroll)

    // one bundle = 3 LDS-DMA gathers + 4 asm B-loads = 7 vmem, order pinned
    auto ISSUE = [&](auto pc) {
        constexpr int p = decltype(pc)::value;
        constexpr int s = p & 3;
        #pragma unroll
        for (int v = 0; v < 3; ++v) {
            const int idx = idxs[irow2 + p * 3 + v];
            const _Float16* src = xg + (long)idx * INF;
            __builtin_amdgcn_global_load_lds((GV*)src, (LV*)(&feat[wave][s][v][0]), 16, 0, 0);
        }
        const char* a = whl + p * 4096;
        asm volatile(
            "global_load_dwordx4 %0, %4, off\n\t"
            "global_load_dwordx4 %1, %4, off offset:1024\n\t"
            "global_load_dwordx4 %2, %4, off offset:2048\n\t"
            "global_load_dwordx4 %3, %4, off offset:3072"
            : "=&v"(bw[s][0]), "=&v"(bw[s][1]), "=&v"(bw[s][2]), "=&v"(bw[s][3])
            : "v"(a)
            : "memory");
        __builtin_amdgcn_sched_barrier(0);
    };

    auto STEP = [&](auto pc) {
        constexpr int p = decltype(pc)::value;
        waitv_sb<(p <= 22) ? 14 : ((p == 23) ? 7 : 0)>();   // bundle p fully retired
        constexpr int s = p & 3;
        const f16x8 v0 = *(const f16x8*)&feat[wave][s][0][roff];
        const f16x8 v1 = *(const f16x8*)&feat[wave][s][1][roff];
        const f16x8 v2 = *(const f16x8*)&feat[wave][s][2][roff];
        const _Float16 w0 = wtsl[wrow + p * 3 + 0];
        const _Float16 w1 = wtsl[wrow + p * 3 + 1];
        const _Float16 w2 = wtsl[wrow + p * 3 + 2];
        const f16x8 af = v0 * w0 + v1 * w1 + v2 * w2;
        #pragma unroll
        for (int nb = 0; nb < 4; ++nb)
            acc[nb] = __builtin_amdgcn_mfma_f32_16x16x32_f16(bw[s][nb], af, acc[nb], 0, 0, 0);
        __builtin_amdgcn_sched_barrier(0);
        if constexpr (p + 3 < NPOS) ISSUE(IC<p + 3>{});
    };

    ISSUE(IC<0>{}); ISSUE(IC<1>{}); ISSUE(IC<2>{});   // 21 vmem in flight

    STEP(IC<0>{});  STEP(IC<1>{});  STEP(IC<2>{});  STEP(IC<3>{});  STEP(IC<4>{});
    STEP(IC<5>{});  STEP(IC<6>{});  STEP(IC<7>{});  STEP(IC<8>{});  STEP(IC<9>{});
    STEP(IC<10>{}); STEP(IC<11>{}); STEP(IC<12>{}); STEP(IC<13>{}); STEP(IC<14>{});
    STEP(IC<15>{}); STEP(IC<16>{}); STEP(IC<17>{}); STEP(IC<18>{}); STEP(IC<19>{});
    STEP(IC<20>{}); STEP(IC<21>{}); STEP(IC<22>{}); STEP(IC<23>{}); STEP(IC<24>{});

    // epilogue: swapped-operand D=[outcol][node] (lineage-verified r4-r9):
    // col(lane&15)=node, rows 4*kgrp+r = outcol -> f32x4 store per nb
    const int node = node0 + arow;
    if (node < NNODES) {
        #pragma unroll
        for (int nb = 0; nb < 4; ++nb) {
            const int cb = 16*nb + 4*kgrp;
            const f32x4 b4 = *(const f32x4*)(bias + cb);
            f32x4 o;
            #pragma unroll
            for (int r = 0; r < 4; ++r) o[r] = acc[nb][r] + b4[r];
            *(f32x4*)(out + (long)node * OUTF + cb) = o;
        }
    }
}

// ---------------- safety fallback (no workspace needed), fp32 ----------------
__global__ void conv_fallback(const float* __restrict__ x, const int* __restrict__ nidx,
                              const float* __restrict__ nwt, const float* __restrict__ W,
                              const float* __restrict__ bias, float* __restrict__ out) {
    __shared__ float feat[KTOT];
    const int n = blockIdx.x;
    const int t = threadIdx.x;   // 64
    for (int e = t; e < KTOT; e += 64) {
        const int p = e >> 5, c = e & 31;
        const int ib = n * 75 + p * 3;
        float a = 0.0f;
        #pragma unroll
        for (int v = 0; v < 3; ++v)
            a += nwt[ib+v] * x[nidx[ib+v] * INF + c];
        feat[e] = a;
    }
    __syncthreads();
    float a = bias[t];
    const float* wr = W + t * KTOT;
    for (int k = 0; k < KTOT; ++k) a += feat[k] * wr[k];
    out[(long)n * OUTF + t] = a;
}

extern "C" void kernel_launch(void* const* d_in, const int* in_sizes, int n_in,
                              void* d_out, int out_size, void* d_ws, size_t ws_size,
                              hipStream_t stream) {
    const float* x    = (const float*)d_in[0];
    const int*   nidx = (const int*)  d_in[1];
    const float* nwt  = (const float*)d_in[2];
    const float* W    = (const float*)d_in[3];
    const float* bias = (const float*)d_in[4];
    float* out = (float*)d_out;

    const size_t need = (size_t)NNODES * INF * 2 + (size_t)NPOS * 4 * 64 * 8 * 2;
    if (ws_size < need) {
        conv_fallback<<<NNODES, 64, 0, stream>>>(x, nidx, nwt, W, bias, out);
        return;
    }

    _Float16* xh = (_Float16*)d_ws;
    _Float16* wh = xh + (size_t)NNODES * INF;

    cvt_kernel<<<1024, NTHREADS, 0, stream>>>(x, W, xh, wh);
    const int nblocks = (NNODES + MT - 1) / MT;   // 2561
    conv_mfma<<<nblocks, NTHREADS, 0, stream>>>(nidx, nwt, xh, wh, bias, out);
}